// Round 1
// baseline (184.048 us; speedup 1.0000x reference)
//
#include <hip/hip_runtime.h>
#include <math.h>

// ClownSelector: windowed router — fused norm + window-mean + logits GEMM +
// top-2 softmax renorm.
//
// Shapes: x[8][2048][1024] fp32, proto[64][1024] fp32, mask unused.
// Out (concat, fp32 buffer): modules[8][2048][2] as float, then weights[8][2048][2].
//
// Algebra used:
//   - window-mean commutes with the expert GEMM (linear) -> per-row dots only
//   - L2 norm is a post-hoc per-row scalar on the dots
//   - top2 renormalized softmax = 1/(1+exp(l2-l1)); full softmax sum cancels

#define BB 8
#define SS 2048
#define DD 1024
#define EE 64
#define TB 64          // tokens per block
#define RR (TB + 2)    // 66 rows incl. causal halo
#define CK 64          // d-chunk staged per K iteration
#define NCK (DD / CK)  // 16
#define XPAD 68        // padded row stride (floats) for xs/cl: +4 breaks bank aliasing
#define EPSV 1e-8f

__global__ __launch_bounds__(256) void clown_router_kernel(
    const float* __restrict__ x, const float* __restrict__ proto,
    float* __restrict__ out) {
  __shared__ float xs[RR][XPAD];   // x rows chunk          (17952 B)
  __shared__ float ps[CK][EE];     // proto^T chunk, XOR-swizzled cols (16384 B)
  __shared__ float cl[RR][XPAD];   // per-row normalized logits (17952 B)
  __shared__ float nsq[RR];        // per-row sum of squares

  const int t  = threadIdx.x;
  const int b  = blockIdx.x >> 5;        // batch
  const int s0 = (blockIdx.x & 31) * TB; // first token of this block

  const int eg = t & 15;   // expert group: experts 4eg..4eg+3
  const int rg = t >> 4;   // row group: rows rg + 16k
  const bool has5 = (rg < 2);  // rows 64,65

  if (t < RR) nsq[t] = 0.0f;

  float acc[5][4];
#pragma unroll
  for (int k = 0; k < 5; ++k)
#pragma unroll
    for (int j = 0; j < 4; ++j) acc[k][j] = 0.0f;

  const float* xb = x + (size_t)b * SS * DD;
  __syncthreads();  // nsq init visible before atomics

  for (int kc = 0; kc < NCK; ++kc) {
    // ---- stage x rows: 66 rows x 64 floats, coalesced float4, fused sumsq ----
    for (int i = t; i < (RR * CK / 4); i += 256) {
      const int row = i >> 4;       // 16 float4 per row
      const int dq  = i & 15;
      int grow = s0 - 2 + row;      // causal halo; clamp replicates token 0
      if (grow < 0) grow = 0;
      const float4 v = *(const float4*)(xb + (size_t)grow * DD + kc * CK + dq * 4);
      *(float4*)(&xs[row][dq * 4]) = v;
      atomicAdd(&nsq[row], v.x * v.x + v.y * v.y + v.z * v.z + v.w * v.w);
    }
    // ---- stage proto^T: ps[d][e ^ (d&60)] — conflict-free store AND read ----
    for (int i = t; i < (EE * CK / 4); i += 256) {
      const int e  = i >> 4;
      const int dq = i & 15;
      const float4 v = *(const float4*)(proto + (size_t)e * DD + kc * CK + dq * 4);
      const int col = e ^ (dq * 4);  // (4dq+m)&60 == 4dq
      ps[4 * dq + 0][col] = v.x;
      ps[4 * dq + 1][col] = v.y;
      ps[4 * dq + 2][col] = v.z;
      ps[4 * dq + 3][col] = v.w;
    }
    __syncthreads();

    // ---- register micro-tile GEMM: 4(+1) rows x 4 experts per thread ----
#pragma unroll 4
    for (int d4 = 0; d4 < CK; d4 += 4) {
      const int pc = (4 * eg) ^ (d4 & 60);
      const float4 p0 = *(const float4*)(&ps[d4 + 0][pc]);
      const float4 p1 = *(const float4*)(&ps[d4 + 1][pc]);
      const float4 p2 = *(const float4*)(&ps[d4 + 2][pc]);
      const float4 p3 = *(const float4*)(&ps[d4 + 3][pc]);
#pragma unroll
      for (int k = 0; k < 4; ++k) {
        const float4 xv = *(const float4*)(&xs[rg + 16 * k][d4]);
        acc[k][0] += xv.x * p0.x + xv.y * p1.x + xv.z * p2.x + xv.w * p3.x;
        acc[k][1] += xv.x * p0.y + xv.y * p1.y + xv.z * p2.y + xv.w * p3.y;
        acc[k][2] += xv.x * p0.z + xv.y * p1.z + xv.z * p2.z + xv.w * p3.z;
        acc[k][3] += xv.x * p0.w + xv.y * p1.w + xv.z * p2.w + xv.w * p3.w;
      }
      if (has5) {
        const float4 xv = *(const float4*)(&xs[rg + 64][d4]);
        acc[4][0] += xv.x * p0.x + xv.y * p1.x + xv.z * p2.x + xv.w * p3.x;
        acc[4][1] += xv.x * p0.y + xv.y * p1.y + xv.z * p2.y + xv.w * p3.y;
        acc[4][2] += xv.x * p0.z + xv.y * p1.z + xv.z * p2.z + xv.w * p3.z;
        acc[4][3] += xv.x * p0.w + xv.y * p1.w + xv.z * p2.w + xv.w * p3.w;
      }
      (void)0;
    }
    __syncthreads();
  }

  // ---- apply 1/max(||x||,eps) and publish per-row logits ----
#pragma unroll
  for (int k = 0; k < 5; ++k) {
    const int row = rg + 16 * k;
    if (row < RR) {
      const float inv = 1.0f / fmaxf(sqrtf(nsq[row]), EPSV);
      float4 cv;
      cv.x = acc[k][0] * inv;
      cv.y = acc[k][1] * inv;
      cv.z = acc[k][2] * inv;
      cv.w = acc[k][3] * inv;
      *(float4*)(&cl[row][4 * eg]) = cv;
    }
  }
  __syncthreads();

  // ---- per-token: window-sum of 3 rows, top-2 over 64 experts ----
  {
    const int tok = t >> 2;  // 0..63
    const int q   = t & 3;   // 16 experts each
    const int li  = tok + 2; // local row of this token
    float v1 = -INFINITY, v2 = -INFINITY;
    int i1 = 0, i2 = 0;
#pragma unroll
    for (int j = 0; j < 16; ++j) {
      const int e = q * 16 + j;
      const float l = cl[li - 2][e] + cl[li - 1][e] + cl[li][e];
      if (l > v1) {
        v2 = v1; i2 = i1; v1 = l; i1 = e;
      } else if (l > v2) {
        v2 = l; i2 = e;
      }
    }
    // merge the 4 partial top-2 sets (lanes 4tok..4tok+3), tie -> lower index
#pragma unroll
    for (int m = 1; m <= 2; m <<= 1) {
      const float ov1 = __shfl_xor(v1, m);
      const int   oi1 = __shfl_xor(i1, m);
      const float ov2 = __shfl_xor(v2, m);
      const int   oi2 = __shfl_xor(i2, m);
      const bool o1_beats_v1 = (ov1 > v1) || (ov1 == v1 && oi1 < i1);
      if (o1_beats_v1) {
        const bool v1_beats_o2 = (v1 > ov2) || (v1 == ov2 && i1 < oi2);
        const float nv2 = v1_beats_o2 ? v1 : ov2;
        const int   ni2 = v1_beats_o2 ? i1 : oi2;
        v1 = ov1; i1 = oi1; v2 = nv2; i2 = ni2;
      } else {
        const bool o1_beats_v2 = (ov1 > v2) || (ov1 == v2 && oi1 < i2);
        if (o1_beats_v2) { v2 = ov1; i2 = oi1; }
      }
    }
    if (q == 0) {
      // logits carry an implicit /3 (window mean); only the gap matters.
      const float ex = expf((v2 - v1) * (1.0f / 3.0f));  // <= 1
      const float w1 = 1.0f / (1.0f + ex);
      const float w2 = ex * w1;
      const int s = s0 + tok;
      const size_t idx = ((size_t)b * SS + s) * 2;
      out[idx]     = (float)i1;   // modules as float (concat buffer is fp32)
      out[idx + 1] = (float)i2;
      out[(size_t)BB * SS * 2 + idx]     = w1;
      out[(size_t)BB * SS * 2 + idx + 1] = w2;
    }
  }
}

extern "C" void kernel_launch(void* const* d_in, const int* in_sizes, int n_in,
                              void* d_out, int out_size, void* d_ws, size_t ws_size,
                              hipStream_t stream) {
  const float* x     = (const float*)d_in[0];
  const float* proto = (const float*)d_in[1];
  // d_in[2] = attn_mask: unused by the reference output path.
  float* out = (float*)d_out;
  dim3 grid(BB * (SS / TB));  // 256 blocks
  dim3 block(256);
  clown_router_kernel<<<grid, block, 0, stream>>>(x, proto, out);
}